// Round 13
// baseline (283.247 us; speedup 1.0000x reference)
//
#include <hip/hip_runtime.h>
#include <stdint.h>

// RBF_euclidean: out[N,128] = P @ coeffs, P[i,g] = exp(-d2(x_i,grid_g)*ln2/w^2)
// Round 13: occupancy-first redesign. Rounds 7-12 showed wall ~ resident waves
// (unified-reg bucket 64/128/256 per m69), per-wave MFMA duty only ~24% due to
// in-loop LDS reads + 2 waves/SIMD. This round:
//  - 32-row x 64-col waves (12500 waves, 2x round 11), 256-thr blocks (4 waves,
//    2x2 split of a 64x128 block tile), NO LDS, NO barriers.
//  - Each lane owns one row: e1a[12]/e2a[12] in regs via own exp2 (same
//    formulas as the old E-tables -> bit-identical); e0i computed per i.
//  - acc = two NAMED f32x16 (32 AGPR); B = 4 f16x8, depth-1 prefetch.
//    Unified regs ~110-125 <= 128 -> 4 waves/SIMD target.
//  - Per-output MFMA operand order unchanged since round 5 -> absmax canary
//    must be exactly 0.03125.

typedef _Float16 f16;
typedef _Float16 f16x8 __attribute__((ext_vector_type(8)));
typedef float f32x16 __attribute__((ext_vector_type(16)));

#define LN2F 0.69314718f
#define LOG2E 1.4426950408889634f

#define CD 128       // codomain dim
#define KD 1728      // dense K

// ---------- prep: regrouped fragment image, f16 hi/lo split (unchanged) ----------
// kp = (i*9+s)*16 + hh*8 + b; type-A s<6: j=2s+hh, k2=b;
// type-B s>=6: j=4(s-6)+2hh+(b>>2), k2=8+(b&3).
// image byte = ((kp>>3)*CD + col)*16 + 2*(kp&7)
__global__ void prep_coeffs(const float* __restrict__ coeffs,
                            f16* __restrict__ ch, f16* __restrict__ cl) {
  int kp  = blockIdx.x * 2 + (threadIdx.x >> 7);   // 0..1727
  int col = threadIdx.x & 127;
  int i   = kp / 144;
  int r   = kp - i * 144;
  int s   = r >> 4;
  int idx = r & 15;
  int hh  = idx >> 3;
  int b   = idx & 7;
  int j, k2;
  if (s < 6) { j = 2 * s + hh;                 k2 = b; }
  else       { j = 4 * (s - 6) + 2 * hh + (b >> 2); k2 = 8 + (b & 3); }
  float v = coeffs[(size_t)((i * 12 + j) * 12 + k2) * CD + col];
  f16 h = (f16)v;
  f16 l = (f16)(v - (float)h);
  size_t o = ((size_t)(kp >> 3) * CD + col) * 8 + (kp & 7);
  ch[o] = h;
  cl[o] = l;
}

union FU { uint32_t u[4]; f16x8 v; };

// ---------- main GEMM: LDS-free, 4 independent waves per block ----------
__global__ __launch_bounds__(256) void rbf_gemm(
    const float* __restrict__ x,
    const float* __restrict__ width,
    const f16* __restrict__ ch, const f16* __restrict__ cl,
    float* __restrict__ out, int N) {
  const int t    = threadIdx.x;
  const int lane = t & 63;
  const int wv   = t >> 6;          // wave 0..3
  const int l31  = lane & 31;
  const int hh   = lane >> 5;       // k-half this lane supplies
  const int wvr  = wv >> 1;         // row half of the 64-row block tile
  const int wvc  = wv & 1;          // col half (64 cols)
  const int rbase = blockIdx.x * 64;

  const float w  = width[0];
  const float s2 = (LN2F * LOG2E) / (w * w);   // p = 2^(-d2*s2)

  // this lane's row (one row per lane; lanes 32-63 mirror rows of 0-31)
  int rr = rbase + wvr * 32 + l31;
  if (rr >= N) rr = N - 1;
  const float x0 = x[(size_t)rr * 3 + 0];
  const float x1 = x[(size_t)rr * 3 + 1];
  const float x2 = x[(size_t)rr * 3 + 2];

  // per-lane axis tables in registers (same formulas as old LDS E-tables)
  float e1a[12], e2a[12];
#pragma unroll
  for (int k = 0; k < 12; ++k) {
    float g  = (float)k * (2.0f / 11.0f) - 1.0f;   // linspace(-1,1,12)
    float d1 = x1 - g;
    float d2 = x2 - g;
    e1a[k] = __builtin_amdgcn_exp2f(-d1 * d1 * s2);
    e2a[k] = __builtin_amdgcn_exp2f(-d2 * d2 * s2);
  }

  // per-lane B base: step q, col wvc*64+nn*32+l31 at q*4096 + (hh*128+col)*16
  const char* gh = (const char*)ch + (size_t)(hh * 128 + wvc * 64 + l31) * 16;
  const char* gl = (const char*)cl + (size_t)(hh * 128 + wvc * 64 + l31) * 16;

  // preload step 0 (2 col-fragments, hi+lo)
  f16x8 cbh0 = *(const f16x8*)(gh);
  f16x8 cbh1 = *(const f16x8*)(gh + 512);
  f16x8 cbl0 = *(const f16x8*)(gl);
  f16x8 cbl1 = *(const f16x8*)(gl + 512);

  f32x16 acc0, acc1;   // named scalars (not arrays)
#pragma unroll
  for (int q = 0; q < 16; ++q) { acc0[q] = 0.f; acc1[q] = 0.f; }

  // macro-loop over i; 9 dense steps fully unrolled
#pragma unroll 1
  for (int i = 0; i < 12; ++i) {
    float gi  = (float)i * (2.0f / 11.0f) - 1.0f;
    float d0  = x0 - gi;
    float e0i = __builtin_amdgcn_exp2f(-d0 * d0 * s2);

#pragma unroll
    for (int s = 0; s < 9; ++s) {
      // prefetch step s+1 (contiguous across i; tail reads land in cl/ws slack)
      const char* ph = gh + (s + 1) * 4096;
      const char* pl = gl + (s + 1) * 4096;
      f16x8 nbh0 = *(const f16x8*)(ph);
      f16x8 nbh1 = *(const f16x8*)(ph + 512);
      f16x8 nbl0 = *(const f16x8*)(pl);
      f16x8 nbl1 = *(const f16x8*)(pl + 512);

      // A fragments (same per-lane values as rounds 8-12)
      FU ah, al;
      if (s < 6) {
        // j = 2s+hh, k2 = b
        float es = e0i * (hh ? e1a[2 * s + 1] : e1a[2 * s]);
#pragma unroll
        for (int q = 0; q < 4; ++q) {
          float ea = e2a[2 * q];
          float eb = e2a[2 * q + 1];
          uint32_t hq, lq;
          asm("v_fma_mixlo_f16 %0, %1, %2, 0"
              : "=v"(hq) : "v"(es), "v"(ea));
          asm("v_fma_mixhi_f16 %0, %1, %2, 0"
              : "+v"(hq) : "v"(es), "v"(eb));
          asm("v_fma_mixlo_f16 %0, %1, %2, -%3 op_sel:[0,0,0] op_sel_hi:[0,0,1]"
              : "=v"(lq) : "v"(es), "v"(ea), "v"(hq));
          asm("v_fma_mixhi_f16 %0, %1, %2, -%3 op_sel:[0,0,1] op_sel_hi:[0,0,1]"
              : "+v"(lq) : "v"(es), "v"(eb), "v"(hq));
          ah.u[q] = hq;
          al.u[q] = lq;
        }
      } else {
        // j = 4(s-6)+2hh+(b>>2), k2 = 8+(b&3)
        int J0 = 4 * (s - 6);
        float c01 = e0i * (hh ? e1a[J0 + 2] : e1a[J0 + 0]);   // b=0..3
        float c23 = e0i * (hh ? e1a[J0 + 3] : e1a[J0 + 1]);   // b=4..7
#pragma unroll
        for (int q = 0; q < 4; ++q) {
          float es = (q < 2) ? c01 : c23;
          float ea = e2a[8 + 2 * (q & 1)];       // k2 = 8 or 10
          float eb = e2a[9 + 2 * (q & 1)];       // k2 = 9 or 11
          uint32_t hq, lq;
          asm("v_fma_mixlo_f16 %0, %1, %2, 0"
              : "=v"(hq) : "v"(es), "v"(ea));
          asm("v_fma_mixhi_f16 %0, %1, %2, 0"
              : "+v"(hq) : "v"(es), "v"(eb));
          asm("v_fma_mixlo_f16 %0, %1, %2, -%3 op_sel:[0,0,0] op_sel_hi:[0,0,1]"
              : "=v"(lq) : "v"(es), "v"(ea), "v"(hq));
          asm("v_fma_mixhi_f16 %0, %1, %2, -%3 op_sel:[0,0,1] op_sel_hi:[0,0,1]"
              : "+v"(lq) : "v"(es), "v"(eb), "v"(hq));
          ah.u[q] = hq;
          al.u[q] = lq;
        }
      }

      // 6 MFMA, per-acc order: ah*bh, al*bh, ah*bl (unchanged since round 5)
      acc0 = __builtin_amdgcn_mfma_f32_32x32x16_f16(ah.v, cbh0, acc0, 0, 0, 0);
      acc1 = __builtin_amdgcn_mfma_f32_32x32x16_f16(ah.v, cbh1, acc1, 0, 0, 0);
      acc0 = __builtin_amdgcn_mfma_f32_32x32x16_f16(al.v, cbh0, acc0, 0, 0, 0);
      acc1 = __builtin_amdgcn_mfma_f32_32x32x16_f16(al.v, cbh1, acc1, 0, 0, 0);
      acc0 = __builtin_amdgcn_mfma_f32_32x32x16_f16(ah.v, cbl0, acc0, 0, 0, 0);
      acc1 = __builtin_amdgcn_mfma_f32_32x32x16_f16(ah.v, cbl1, acc1, 0, 0, 0);

      // rotate prefetch registers (SSA renaming)
      cbh0 = nbh0; cbh1 = nbh1; cbl0 = nbl0; cbl1 = nbl1;
    }
    gh += 9 * 4096;
    gl += 9 * 4096;
  }

  // epilogue: 32x32 D layout: col=lane&31, row=(q&3)+8*(q>>2)+4*(lane>>5)
#pragma unroll
  for (int q = 0; q < 16; ++q) {
    int row = rbase + wvr * 32 + (q & 3) + 8 * (q >> 2) + 4 * hh;
    if (row < N) {
      int col = wvc * 64 + l31;
      out[(size_t)row * CD + col]      = acc0[q];
      out[(size_t)row * CD + col + 32] = acc1[q];
    }
  }
}

// ---------- slow-but-correct fallback (only if ws is too small) ----------
__global__ void rbf_fallback(const float* __restrict__ x, const float* __restrict__ grid,
                             const float* __restrict__ coeffs, const float* __restrict__ width,
                             float* __restrict__ out, int N) {
  int row = blockIdx.x;
  int col = threadIdx.x;
  if (row >= N) return;
  float x0 = x[(size_t)row * 3 + 0];
  float x1 = x[(size_t)row * 3 + 1];
  float x2 = x[(size_t)row * 3 + 2];
  float w = width[0];
  float s2 = (LN2F * LOG2E) / (w * w);
  float acc = 0.f;
  for (int g = 0; g < 1728; ++g) {
    float d0 = x0 - grid[g * 3 + 0];
    float d1 = x1 - grid[g * 3 + 1];
    float d2 = x2 - grid[g * 3 + 2];
    float p = exp2f(-(d0 * d0 + d1 * d1 + d2 * d2) * s2);
    acc += p * coeffs[(size_t)g * CD + col];
  }
  out[(size_t)row * CD + col] = acc;
}

extern "C" void kernel_launch(void* const* d_in, const int* in_sizes, int n_in,
                              void* d_out, int out_size, void* d_ws, size_t ws_size,
                              hipStream_t stream) {
  const float* x      = (const float*)d_in[0];
  const float* grid   = (const float*)d_in[1];
  const float* coeffs = (const float*)d_in[2];
  const float* width  = (const float*)d_in[3];
  float* out = (float*)d_out;
  int N = in_sizes[0] / 3;

  // image = 2 * KD*CD f16 = 884736 B; + slack for the tail prefetch
  size_t need = (size_t)2 * CD * KD * sizeof(f16) + 16384;
  if (ws_size >= need) {
    f16* ch = (f16*)d_ws;
    f16* cl = ch + (size_t)CD * KD;
    hipLaunchKernelGGL(prep_coeffs, dim3(KD / 2), dim3(256), 0, stream,
                       coeffs, ch, cl);
    int nb = (N + 63) / 64;
    hipLaunchKernelGGL(rbf_gemm, dim3(nb), dim3(256), 0, stream,
                       x, width, ch, cl, out, N);
  } else {
    hipLaunchKernelGGL(rbf_fallback, dim3(N), dim3(CD), 0, stream,
                       x, grid, coeffs, width, out, N);
  }
}

// Round 14
// 264.525 us; speedup vs baseline: 1.0708x; 1.0708x over previous
//
#include <hip/hip_runtime.h>
#include <stdint.h>

// RBF_euclidean: out[N,128] = P @ coeffs, P[i,g] = exp(-d2(x_i,grid_g)*ln2/w^2)
// Round 14: r13 wave body (passed, absmax 0.03125) restructured for the three
// constraints the counter history exposed:
//  (1) many resident waves  -> 52+32 regs, 128-bucket, 4 waves/SIMD
//  (2) low B L2-traffic     -> 4 waves/block share the SAME 64 cols; block
//      waves sit on different SIMDs in near-lockstep -> identical B addresses
//      hit L1 -> L2 traffic / 4 (~1.35 GB)
//  (3) MFMA||VALU phase diversity -> each SIMD hosts waves of 4 DIFFERENT
//      blocks (different phases), fixing the sum-not-max pipe serialization
//  VALU diet: merged hi/lo image [step][colhalf][hi|lo] (8KB/step): loads are
//  saddr(uniform step base)+voffset+imm (0/512/2048/2560) - no per-step addr VALU.
//  Per-output FP op sequence identical to r13 -> absmax must be 0.03125.

typedef _Float16 f16;
typedef _Float16 f16x8 __attribute__((ext_vector_type(8)));
typedef float f32x16 __attribute__((ext_vector_type(16)));

#define LN2F 0.69314718f
#define LOG2E 1.4426950408889634f

#define CD 128       // codomain dim
#define KD 1728      // dense K (108 steps of 16)

// ---------- prep: regrouped merged image ----------
// kp = (i*9+s)*16 + hh*8 + b; type-A s<6: j=2s+hh, k2=b;
// type-B s>=6: j=4(s-6)+2hh+(b>>2), k2=8+(b&3).
// f16 index: q*4096 + ch2*2048 + hh*512 + c64*8 + b  (hi);  +1024 (lo)
//   where q=i*9+s, ch2=col>>6, c64=col&63.
__global__ void prep_coeffs(const float* __restrict__ coeffs,
                            f16* __restrict__ img) {
  int kp  = blockIdx.x * 2 + (threadIdx.x >> 7);   // 0..1727
  int col = threadIdx.x & 127;
  int i   = kp / 144;
  int r   = kp - i * 144;
  int s   = r >> 4;
  int idx = r & 15;
  int hh  = idx >> 3;
  int b   = idx & 7;
  int j, k2;
  if (s < 6) { j = 2 * s + hh;                 k2 = b; }
  else       { j = 4 * (s - 6) + 2 * hh + (b >> 2); k2 = 8 + (b & 3); }
  float v = coeffs[(size_t)((i * 12 + j) * 12 + k2) * CD + col];
  f16 h = (f16)v;
  f16 l = (f16)(v - (float)h);
  int q   = i * 9 + s;
  int ch2 = col >> 6;
  int c64 = col & 63;
  size_t o = (size_t)q * 4096 + ch2 * 2048 + hh * 512 + c64 * 8 + b;
  img[o]        = h;
  img[o + 1024] = l;
}

union FU { uint32_t u[4]; f16x8 v; };

// ---------- main GEMM: LDS-free, 4 waves/block sharing one 64-col strip ----------
__global__ __launch_bounds__(256) void rbf_gemm(
    const float* __restrict__ x,
    const float* __restrict__ width,
    const f16* __restrict__ img,
    float* __restrict__ out, int N) {
  const int t    = threadIdx.x;
  const int lane = t & 63;
  const int wv   = t >> 6;          // wave 0..3: 32-row strips of the block
  const int l31  = lane & 31;
  const int hh   = lane >> 5;       // k-half this lane supplies
  const int rbase = blockIdx.x * 128;
  const int ch2   = blockIdx.y;     // 64-col half

  const float w  = width[0];
  const float s2 = (LN2F * LOG2E) / (w * w);   // p = 2^(-d2*s2)

  // this lane's row (lanes 32-63 mirror rows of 0-31)
  int rr = rbase + wv * 32 + l31;
  if (rr >= N) rr = N - 1;
  const float x0 = x[(size_t)rr * 3 + 0];
  const float x1 = x[(size_t)rr * 3 + 1];
  const float x2 = x[(size_t)rr * 3 + 2];

  // per-lane axis tables in registers (same formulas as r13 -> bit-identical)
  float e1a[12], e2a[12];
#pragma unroll
  for (int k = 0; k < 12; ++k) {
    float g  = (float)k * (2.0f / 11.0f) - 1.0f;   // linspace(-1,1,12)
    float d1 = x1 - g;
    float d2 = x2 - g;
    e1a[k] = __builtin_amdgcn_exp2f(-d1 * d1 * s2);
    e2a[k] = __builtin_amdgcn_exp2f(-d2 * d2 * s2);
  }

  // per-lane byte offset within a step block (divergent, 32-bit)
  const int voff = ch2 * 4096 + hh * 1024 + l31 * 16;
  const char* imgb = (const char*)img;

  // preload step 0: hi0, hi1, lo0, lo1
  f16x8 cb0 = *(const f16x8*)(imgb + voff + 0);
  f16x8 cb1 = *(const f16x8*)(imgb + voff + 512);
  f16x8 cb2 = *(const f16x8*)(imgb + voff + 2048);
  f16x8 cb3 = *(const f16x8*)(imgb + voff + 2560);

  f32x16 acc0, acc1;   // named (not arrays)
#pragma unroll
  for (int q = 0; q < 16; ++q) { acc0[q] = 0.f; acc1[q] = 0.f; }

  // macro-loop over i; 9 dense steps fully unrolled
#pragma unroll 1
  for (int i = 0; i < 12; ++i) {
    float gi  = (float)i * (2.0f / 11.0f) - 1.0f;
    float d0  = x0 - gi;
    float e0i = __builtin_amdgcn_exp2f(-d0 * d0 * s2);

#pragma unroll
    for (int s = 0; s < 9; ++s) {
      // prefetch next step (uniform SGPR base advances; tail lands in ws slack)
      const char* spn = imgb + (size_t)(i * 9 + s + 1) * 8192;
      f16x8 nb0 = *(const f16x8*)(spn + voff + 0);
      f16x8 nb1 = *(const f16x8*)(spn + voff + 512);
      f16x8 nb2 = *(const f16x8*)(spn + voff + 2048);
      f16x8 nb3 = *(const f16x8*)(spn + voff + 2560);

      // A fragments (identical values/ops to r13)
      FU ah, al;
      if (s < 6) {
        // j = 2s+hh, k2 = b
        float es = e0i * (hh ? e1a[2 * s + 1] : e1a[2 * s]);
#pragma unroll
        for (int q = 0; q < 4; ++q) {
          float ea = e2a[2 * q];
          float eb = e2a[2 * q + 1];
          uint32_t hq, lq;
          asm("v_fma_mixlo_f16 %0, %1, %2, 0"
              : "=v"(hq) : "v"(es), "v"(ea));
          asm("v_fma_mixhi_f16 %0, %1, %2, 0"
              : "+v"(hq) : "v"(es), "v"(eb));
          asm("v_fma_mixlo_f16 %0, %1, %2, -%3 op_sel:[0,0,0] op_sel_hi:[0,0,1]"
              : "=v"(lq) : "v"(es), "v"(ea), "v"(hq));
          asm("v_fma_mixhi_f16 %0, %1, %2, -%3 op_sel:[0,0,1] op_sel_hi:[0,0,1]"
              : "+v"(lq) : "v"(es), "v"(eb), "v"(hq));
          ah.u[q] = hq;
          al.u[q] = lq;
        }
      } else {
        // j = 4(s-6)+2hh+(b>>2), k2 = 8+(b&3)
        int J0 = 4 * (s - 6);
        float c01 = e0i * (hh ? e1a[J0 + 2] : e1a[J0 + 0]);   // b=0..3
        float c23 = e0i * (hh ? e1a[J0 + 3] : e1a[J0 + 1]);   // b=4..7
#pragma unroll
        for (int q = 0; q < 4; ++q) {
          float es = (q < 2) ? c01 : c23;
          float ea = e2a[8 + 2 * (q & 1)];       // k2 = 8 or 10
          float eb = e2a[9 + 2 * (q & 1)];       // k2 = 9 or 11
          uint32_t hq, lq;
          asm("v_fma_mixlo_f16 %0, %1, %2, 0"
              : "=v"(hq) : "v"(es), "v"(ea));
          asm("v_fma_mixhi_f16 %0, %1, %2, 0"
              : "+v"(hq) : "v"(es), "v"(eb));
          asm("v_fma_mixlo_f16 %0, %1, %2, -%3 op_sel:[0,0,0] op_sel_hi:[0,0,1]"
              : "=v"(lq) : "v"(es), "v"(ea), "v"(hq));
          asm("v_fma_mixhi_f16 %0, %1, %2, -%3 op_sel:[0,0,1] op_sel_hi:[0,0,1]"
              : "+v"(lq) : "v"(es), "v"(eb), "v"(hq));
          ah.u[q] = hq;
          al.u[q] = lq;
        }
      }

      // 6 MFMA, per-acc order: ah*bh, al*bh, ah*bl (unchanged since round 5)
      acc0 = __builtin_amdgcn_mfma_f32_32x32x16_f16(ah.v, cb0, acc0, 0, 0, 0);
      acc1 = __builtin_amdgcn_mfma_f32_32x32x16_f16(ah.v, cb1, acc1, 0, 0, 0);
      acc0 = __builtin_amdgcn_mfma_f32_32x32x16_f16(al.v, cb0, acc0, 0, 0, 0);
      acc1 = __builtin_amdgcn_mfma_f32_32x32x16_f16(al.v, cb1, acc1, 0, 0, 0);
      acc0 = __builtin_amdgcn_mfma_f32_32x32x16_f16(ah.v, cb2, acc0, 0, 0, 0);
      acc1 = __builtin_amdgcn_mfma_f32_32x32x16_f16(ah.v, cb3, acc1, 0, 0, 0);

      // rotate prefetch registers (straightline -> renamed, no movs)
      cb0 = nb0; cb1 = nb1; cb2 = nb2; cb3 = nb3;
    }
  }

  // epilogue: 32x32 D layout: col=lane&31, row=(q&3)+8*(q>>2)+4*(lane>>5)
#pragma unroll
  for (int q = 0; q < 16; ++q) {
    int row = rbase + wv * 32 + (q & 3) + 8 * (q >> 2) + 4 * hh;
    if (row < N) {
      int col = ch2 * 64 + l31;
      out[(size_t)row * CD + col]      = acc0[q];
      out[(size_t)row * CD + col + 32] = acc1[q];
    }
  }
}

// ---------- slow-but-correct fallback (only if ws is too small) ----------
__global__ void rbf_fallback(const float* __restrict__ x, const float* __restrict__ grid,
                             const float* __restrict__ coeffs, const float* __restrict__ width,
                             float* __restrict__ out, int N) {
  int row = blockIdx.x;
  int col = threadIdx.x;
  if (row >= N) return;
  float x0 = x[(size_t)row * 3 + 0];
  float x1 = x[(size_t)row * 3 + 1];
  float x2 = x[(size_t)row * 3 + 2];
  float w = width[0];
  float s2 = (LN2F * LOG2E) / (w * w);
  float acc = 0.f;
  for (int g = 0; g < 1728; ++g) {
    float d0 = x0 - grid[g * 3 + 0];
    float d1 = x1 - grid[g * 3 + 1];
    float d2 = x2 - grid[g * 3 + 2];
    float p = exp2f(-(d0 * d0 + d1 * d1 + d2 * d2) * s2);
    acc += p * coeffs[(size_t)g * CD + col];
  }
  out[(size_t)row * CD + col] = acc;
}

extern "C" void kernel_launch(void* const* d_in, const int* in_sizes, int n_in,
                              void* d_out, int out_size, void* d_ws, size_t ws_size,
                              hipStream_t stream) {
  const float* x      = (const float*)d_in[0];
  const float* grid   = (const float*)d_in[1];
  const float* coeffs = (const float*)d_in[2];
  const float* width  = (const float*)d_in[3];
  float* out = (float*)d_out;
  int N = in_sizes[0] / 3;

  // image = KD*CD*2 f16 = 884736 B; + slack for the tail prefetch (step 108)
  size_t need = (size_t)KD * CD * 2 * sizeof(f16) + 16384;
  if (ws_size >= need) {
    f16* img = (f16*)d_ws;
    hipLaunchKernelGGL(prep_coeffs, dim3(KD / 2), dim3(256), 0, stream,
                       coeffs, img);
    int nb = (N + 127) / 128;
    hipLaunchKernelGGL(rbf_gemm, dim3(nb, 2), dim3(256), 0, stream,
                       x, width, img, out, N);
  } else {
    hipLaunchKernelGGL(rbf_fallback, dim3(N), dim3(CD), 0, stream,
                       x, grid, coeffs, width, out, N);
  }
}

// Round 15
// 246.109 us; speedup vs baseline: 1.1509x; 1.0748x over previous
//
#include <hip/hip_runtime.h>
#include <stdint.h>

// RBF_euclidean: out[N,128] = P @ coeffs, P[i,g] = exp(-d2(x_i,grid_g)*ln2/w^2)
// Round 15: convergence of the measured-best elements:
//  - r11 geometry: 64-row x 64-col waves (6252 waves, B L1-traffic 2.7GB=69us,
//    12 MFMA/step/wave duty) - best measured wall (249us).
//  - r13/14 reg-only A-gen: e1a/e2a[2][12] per lane, NO LDS, NO barriers ->
//    no ds_read latency in the A-gen dependency chain.
//  - depth-3 B prefetch (named sets cb->db->nb): ~2 full steps (~580cyc) of
//    in-flight cover vs L2 ~300-500cyc (r13/14's depth-1 was the stall).
//  - r14 merged image [step][ch2][hh][hi|lo]: one pointer, 4 loads/step.
//  - s_setprio(1) around the 12-MFMA cluster (drifted-phase regime, T5).
//  Per-output FP op sequence unchanged since round 5 -> absmax must be 0.03125.

typedef _Float16 f16;
typedef _Float16 f16x8 __attribute__((ext_vector_type(8)));
typedef float f32x16 __attribute__((ext_vector_type(16)));

#define LN2F 0.69314718f
#define LOG2E 1.4426950408889634f

#define CD 128       // codomain dim
#define KD 1728      // dense K (108 steps of 16)

// ---------- prep: regrouped merged image (identical to round 14) ----------
// kp = (i*9+s)*16 + hh*8 + b; type-A s<6: j=2s+hh, k2=b;
// type-B s>=6: j=4(s-6)+2hh+(b>>2), k2=8+(b&3).
// f16 index: q*4096 + ch2*2048 + hh*512 + c64*8 + b (hi); +1024 (lo)
__global__ void prep_coeffs(const float* __restrict__ coeffs,
                            f16* __restrict__ img) {
  int kp  = blockIdx.x * 2 + (threadIdx.x >> 7);   // 0..1727
  int col = threadIdx.x & 127;
  int i   = kp / 144;
  int r   = kp - i * 144;
  int s   = r >> 4;
  int idx = r & 15;
  int hh  = idx >> 3;
  int b   = idx & 7;
  int j, k2;
  if (s < 6) { j = 2 * s + hh;                 k2 = b; }
  else       { j = 4 * (s - 6) + 2 * hh + (b >> 2); k2 = 8 + (b & 3); }
  float v = coeffs[(size_t)((i * 12 + j) * 12 + k2) * CD + col];
  f16 h = (f16)v;
  f16 l = (f16)(v - (float)h);
  int q   = i * 9 + s;
  int ch2 = col >> 6;
  int c64 = col & 63;
  size_t o = (size_t)q * 4096 + ch2 * 2048 + hh * 512 + c64 * 8 + b;
  img[o]        = h;
  img[o + 1024] = l;
}

union FU { uint32_t u[4]; f16x8 v; };

// ---------- main GEMM: LDS-free, 2 waves/block, 64x64 per wave ----------
__global__ __launch_bounds__(128) void rbf_gemm(
    const float* __restrict__ x,
    const float* __restrict__ width,
    const f16* __restrict__ img,
    float* __restrict__ out, int N) {
  const int t    = threadIdx.x;
  const int lane = t & 63;
  const int wv   = t >> 6;          // wave 0..1: 64-row strips
  const int l31  = lane & 31;
  const int hh   = lane >> 5;       // k-half this lane supplies
  const int rbase = blockIdx.x * 128;
  const int ch2   = blockIdx.y;     // 64-col half

  const float w  = width[0];
  const float s2 = (LN2F * LOG2E) / (w * w);   // p = 2^(-d2*s2)

  // this lane's two rows (mi=0: rl0, mi=1: rl0+32)
  int r0 = rbase + wv * 64 + l31;      if (r0 >= N) r0 = N - 1;
  int r1 = rbase + wv * 64 + 32 + l31; if (r1 >= N) r1 = N - 1;
  const float x00 = x[(size_t)r0 * 3 + 0];
  const float x01 = x[(size_t)r0 * 3 + 1];
  const float x02 = x[(size_t)r0 * 3 + 2];
  const float x10 = x[(size_t)r1 * 3 + 0];
  const float x11 = x[(size_t)r1 * 3 + 1];
  const float x12 = x[(size_t)r1 * 3 + 2];

  // per-lane axis tables in registers (same formulas as r13/r14)
  float e1a[2][12], e2a[2][12];
#pragma unroll
  for (int k = 0; k < 12; ++k) {
    float g = (float)k * (2.0f / 11.0f) - 1.0f;   // linspace(-1,1,12)
    float d;
    d = x01 - g; e1a[0][k] = __builtin_amdgcn_exp2f(-d * d * s2);
    d = x11 - g; e1a[1][k] = __builtin_amdgcn_exp2f(-d * d * s2);
    d = x02 - g; e2a[0][k] = __builtin_amdgcn_exp2f(-d * d * s2);
    d = x12 - g; e2a[1][k] = __builtin_amdgcn_exp2f(-d * d * s2);
  }

  // per-lane byte offset within a step block; fragments at +0,+512 (hi) and
  // +2048,+2560 (lo)
  const int voff = ch2 * 4096 + hh * 1024 + l31 * 16;
  const char* imgb = (const char*)img;

  // prologue: steps 0 (cb) and 1 (db) in registers/in flight
  f16x8 cb0 = *(const f16x8*)(imgb + voff + 0);
  f16x8 cb1 = *(const f16x8*)(imgb + voff + 512);
  f16x8 cb2 = *(const f16x8*)(imgb + voff + 2048);
  f16x8 cb3 = *(const f16x8*)(imgb + voff + 2560);
  f16x8 db0 = *(const f16x8*)(imgb + 8192 + voff + 0);
  f16x8 db1 = *(const f16x8*)(imgb + 8192 + voff + 512);
  f16x8 db2 = *(const f16x8*)(imgb + 8192 + voff + 2048);
  f16x8 db3 = *(const f16x8*)(imgb + 8192 + voff + 2560);

  f32x16 acc00, acc01, acc10, acc11;   // named (no arrays)
#pragma unroll
  for (int q = 0; q < 16; ++q) { acc00[q] = 0.f; acc01[q] = 0.f; acc10[q] = 0.f; acc11[q] = 0.f; }

  // macro-loop over i; 9 dense steps fully unrolled
#pragma unroll 1
  for (int i = 0; i < 12; ++i) {
    float gi = (float)i * (2.0f / 11.0f) - 1.0f;
    float d0;
    d0 = x00 - gi; float e00 = __builtin_amdgcn_exp2f(-d0 * d0 * s2);
    d0 = x10 - gi; float e01v = __builtin_amdgcn_exp2f(-d0 * d0 * s2);

#pragma unroll
    for (int s = 0; s < 9; ++s) {
      // prefetch step qidx+2 into nb (uniform base; tail lands in ws slack)
      const char* spn = imgb + (size_t)(i * 9 + s + 2) * 8192;
      f16x8 nb0 = *(const f16x8*)(spn + voff + 0);
      f16x8 nb1 = *(const f16x8*)(spn + voff + 512);
      f16x8 nb2 = *(const f16x8*)(spn + voff + 2048);
      f16x8 nb3 = *(const f16x8*)(spn + voff + 2560);

      // A fragments (values identical to rounds 8-14)
      FU ah0, al0, ah1, al1;
#pragma unroll
      for (int mi = 0; mi < 2; ++mi) {
        float e0i = mi ? e01v : e00;
        FU* pah = mi ? &ah1 : &ah0;
        FU* pal = mi ? &al1 : &al0;
        if (s < 6) {
          float es = e0i * (hh ? e1a[mi][2 * s + 1] : e1a[mi][2 * s]);
#pragma unroll
          for (int q = 0; q < 4; ++q) {
            float ea = e2a[mi][2 * q];
            float eb = e2a[mi][2 * q + 1];
            uint32_t hq, lq;
            asm("v_fma_mixlo_f16 %0, %1, %2, 0"
                : "=v"(hq) : "v"(es), "v"(ea));
            asm("v_fma_mixhi_f16 %0, %1, %2, 0"
                : "+v"(hq) : "v"(es), "v"(eb));
            asm("v_fma_mixlo_f16 %0, %1, %2, -%3 op_sel:[0,0,0] op_sel_hi:[0,0,1]"
                : "=v"(lq) : "v"(es), "v"(ea), "v"(hq));
            asm("v_fma_mixhi_f16 %0, %1, %2, -%3 op_sel:[0,0,1] op_sel_hi:[0,0,1]"
                : "+v"(lq) : "v"(es), "v"(eb), "v"(hq));
            pah->u[q] = hq;
            pal->u[q] = lq;
          }
        } else {
          int J0 = 4 * (s - 6);
          float c01 = e0i * (hh ? e1a[mi][J0 + 2] : e1a[mi][J0 + 0]);   // b=0..3
          float c23 = e0i * (hh ? e1a[mi][J0 + 3] : e1a[mi][J0 + 1]);   // b=4..7
#pragma unroll
          for (int q = 0; q < 4; ++q) {
            float es = (q < 2) ? c01 : c23;
            float ea = e2a[mi][8 + 2 * (q & 1)];       // k2 = 8 or 10
            float eb = e2a[mi][9 + 2 * (q & 1)];       // k2 = 9 or 11
            uint32_t hq, lq;
            asm("v_fma_mixlo_f16 %0, %1, %2, 0"
                : "=v"(hq) : "v"(es), "v"(ea));
            asm("v_fma_mixhi_f16 %0, %1, %2, 0"
                : "+v"(hq) : "v"(es), "v"(eb));
            asm("v_fma_mixlo_f16 %0, %1, %2, -%3 op_sel:[0,0,0] op_sel_hi:[0,0,1]"
                : "=v"(lq) : "v"(es), "v"(ea), "v"(hq));
            asm("v_fma_mixhi_f16 %0, %1, %2, -%3 op_sel:[0,0,1] op_sel_hi:[0,0,1]"
                : "+v"(lq) : "v"(es), "v"(eb), "v"(hq));
            pah->u[q] = hq;
            pal->u[q] = lq;
          }
        }
      }

      // 12 MFMA, per-acc order: ah*bh, al*bh, ah*bl (unchanged since round 5)
      __builtin_amdgcn_s_setprio(1);
      acc00 = __builtin_amdgcn_mfma_f32_32x32x16_f16(ah0.v, cb0, acc00, 0, 0, 0);
      acc01 = __builtin_amdgcn_mfma_f32_32x32x16_f16(ah0.v, cb1, acc01, 0, 0, 0);
      acc10 = __builtin_amdgcn_mfma_f32_32x32x16_f16(ah1.v, cb0, acc10, 0, 0, 0);
      acc11 = __builtin_amdgcn_mfma_f32_32x32x16_f16(ah1.v, cb1, acc11, 0, 0, 0);
      acc00 = __builtin_amdgcn_mfma_f32_32x32x16_f16(al0.v, cb0, acc00, 0, 0, 0);
      acc01 = __builtin_amdgcn_mfma_f32_32x32x16_f16(al0.v, cb1, acc01, 0, 0, 0);
      acc10 = __builtin_amdgcn_mfma_f32_32x32x16_f16(al1.v, cb0, acc10, 0, 0, 0);
      acc11 = __builtin_amdgcn_mfma_f32_32x32x16_f16(al1.v, cb1, acc11, 0, 0, 0);
      acc00 = __builtin_amdgcn_mfma_f32_32x32x16_f16(ah0.v, cb2, acc00, 0, 0, 0);
      acc01 = __builtin_amdgcn_mfma_f32_32x32x16_f16(ah0.v, cb3, acc01, 0, 0, 0);
      acc10 = __builtin_amdgcn_mfma_f32_32x32x16_f16(ah1.v, cb2, acc10, 0, 0, 0);
      acc11 = __builtin_amdgcn_mfma_f32_32x32x16_f16(ah1.v, cb3, acc11, 0, 0, 0);
      __builtin_amdgcn_s_setprio(0);

      // rotate prefetch sets (SSA renaming)
      cb0 = db0; cb1 = db1; cb2 = db2; cb3 = db3;
      db0 = nb0; db1 = nb1; db2 = nb2; db3 = nb3;
    }
  }

  // epilogue: 32x32 D layout: col=lane&31, row=(q&3)+8*(q>>2)+4*(lane>>5)
#pragma unroll
  for (int q = 0; q < 16; ++q) {
    int row0 = rbase + wv * 64 + (q & 3) + 8 * (q >> 2) + 4 * hh;
    int col  = ch2 * 64 + l31;
    if (row0 < N) {
      out[(size_t)row0 * CD + col]      = acc00[q];
      out[(size_t)row0 * CD + col + 32] = acc01[q];
    }
    int row1 = row0 + 32;
    if (row1 < N) {
      out[(size_t)row1 * CD + col]      = acc10[q];
      out[(size_t)row1 * CD + col + 32] = acc11[q];
    }
  }
}

// ---------- slow-but-correct fallback (only if ws is too small) ----------
__global__ void rbf_fallback(const float* __restrict__ x, const float* __restrict__ grid,
                             const float* __restrict__ coeffs, const float* __restrict__ width,
                             float* __restrict__ out, int N) {
  int row = blockIdx.x;
  int col = threadIdx.x;
  if (row >= N) return;
  float x0 = x[(size_t)row * 3 + 0];
  float x1 = x[(size_t)row * 3 + 1];
  float x2 = x[(size_t)row * 3 + 2];
  float w = width[0];
  float s2 = (LN2F * LOG2E) / (w * w);
  float acc = 0.f;
  for (int g = 0; g < 1728; ++g) {
    float d0 = x0 - grid[g * 3 + 0];
    float d1 = x1 - grid[g * 3 + 1];
    float d2 = x2 - grid[g * 3 + 2];
    float p = exp2f(-(d0 * d0 + d1 * d1 + d2 * d2) * s2);
    acc += p * coeffs[(size_t)g * CD + col];
  }
  out[(size_t)row * CD + col] = acc;
}

extern "C" void kernel_launch(void* const* d_in, const int* in_sizes, int n_in,
                              void* d_out, int out_size, void* d_ws, size_t ws_size,
                              hipStream_t stream) {
  const float* x      = (const float*)d_in[0];
  const float* grid   = (const float*)d_in[1];
  const float* coeffs = (const float*)d_in[2];
  const float* width  = (const float*)d_in[3];
  float* out = (float*)d_out;
  int N = in_sizes[0] / 3;

  // image = 108 steps * 8192 B = 884736 B; + 2-step slack for depth-3 prefetch
  size_t need = (size_t)108 * 8192 + 2 * 8192;
  if (ws_size >= need) {
    f16* img = (f16*)d_ws;
    hipLaunchKernelGGL(prep_coeffs, dim3(KD / 2), dim3(256), 0, stream,
                       coeffs, img);
    int nb = (N + 127) / 128;
    hipLaunchKernelGGL(rbf_gemm, dim3(nb, 2), dim3(128), 0, stream,
                       x, width, img, out, N);
  } else {
    hipLaunchKernelGGL(rbf_fallback, dim3(N), dim3(CD), 0, stream,
                       x, grid, coeffs, width, out, N);
  }
}